// Round 7
// baseline (213.151 us; speedup 1.0000x reference)
//
#include <hip/hip_runtime.h>
#include <stdint.h>

// ---------------------------------------------------------------------------
// VectorQuantizer: argmin_k ||x_n - c_k||^2 + straight-through out + losses.
//
// Token semantics (R4/R5/R7/R9-verified): candidates by continuous score
// s = ||c||^2 - 2 x.c via fp16 MFMA; exact fp64 re-score; token = lowest
// index within 0.75*ulp_fp32(Dmin) of the minimum.
//
// R15: swizzled global_load_lds dbuf B: gemm 103us, zero spill/conflicts.
// R16: A panel persistent in 128 VGPRs: gemm 74us. R17: lane-parallel
// refine selection (80 -> <70us): total 203us.
// R18: counted-vmcnt pipeline (T3/T4-lite). __syncthreads drained vmcnt(0)
//   every K-step (the m97-structure stall). Now: 4-buffer B rotation
//   (32KB), raw s_barrier + asm s_waitcnt vmcnt(4) -- the next 2 slices'
//   DMAs stay in flight across barriers (tail: 2/0). kt x dc fully
//   unrolled so vmcnt counts / buffer indices / csq_r regs are all
//   compile-time; csq preloaded to 16 regs so the epilogue issues zero
//   VMEM (no hidden re-drain). Race audit: buf overwritten at s+3 was
//   consumed at s-1; all waves' reads of it completed before their
//   barrier entry at s (lgkm-ordered before MFMA); own vmcnt(4) before
//   barrier proves stage(s) landed.
// ---------------------------------------------------------------------------

#define N_ROWS 16384
#define DIM    256
#define KCODES 4096
#define NCHUNK 8
#define KC     (KCODES / NCHUNK)   // 512 codes per chunk
#define TM     128                 // rows per block tile
#define TN     128                 // codes per code-tile
#define BK     32                  // K per dc step
#define NKT    (KC / TN)           // 4 code tiles per chunk
#define NDC    (DIM / BK)          // 8 K-steps
#define NSTEP  (NKT * NDC)         // 32 pipeline steps
#define NGRAN  (NCHUNK * 2)        // 16 granules of 256 cols (chunk x chalf)
#define NRB    (N_ROWS / TM)       // 128 row-blocks

typedef float    f32x4 __attribute__((ext_vector_type(4)));
typedef _Float16 f16x8 __attribute__((ext_vector_type(8)));

#define GLOAD_LDS16(g, l) __builtin_amdgcn_global_load_lds(                 \
    (const __attribute__((address_space(1))) void*)(g),                     \
    (__attribute__((address_space(3))) void*)(l), 16, 0, 0)

#define WAITVM(n) asm volatile("s_waitcnt vmcnt(" #n ")" ::: "memory")

__device__ __forceinline__ unsigned umin_(unsigned a, unsigned b) { return a < b ? a : b; }
__device__ __forceinline__ unsigned umax_(unsigned a, unsigned b) { return a > b ? a : b; }
__device__ __forceinline__ unsigned long long umin64_(unsigned long long a,
                                                      unsigned long long b) {
    return a < b ? a : b;
}
__device__ __forceinline__ unsigned long long umax64_(unsigned long long a,
                                                      unsigned long long b) {
    return a > b ? a : b;
}

// order-preserving float->uint key
__device__ __forceinline__ unsigned fkey(float f) {
    unsigned b = __float_as_uint(f);
    return (b & 0x80000000u) ? ~b : (b | 0x80000000u);
}
__device__ __forceinline__ float fkey_inv(unsigned k) {
    unsigned b = (k & 0x80000000u) ? (k ^ 0x80000000u) : ~k;
    return __uint_as_float(b);
}
__device__ __forceinline__ unsigned short f2h(float f) {
    union { _Float16 h; unsigned short u; } cv;
    cv.h = (_Float16)f;            // v_cvt_f16_f32, RNE
    return cv.u;
}

// ---- prep: fp16 cast + row sumsq (fp64->fp32) + buffer init, fused ----
__global__ __launch_bounds__(256) void vq_prep_kernel(
        const float* __restrict__ x, const float* __restrict__ cb,
        unsigned short* __restrict__ xh, unsigned short* __restrict__ ch,
        float* __restrict__ xsq, float* __restrict__ csq,
        unsigned* __restrict__ active, double* __restrict__ accum,
        unsigned* __restrict__ counter) {
    const int b = blockIdx.x, t = threadIdx.x;
    if (b < KCODES / 256) {
        int i = b * 256 + t;
        active[i] = 0u;
        if (i == 0) { accum[0] = 0.0; accum[1] = 0.0; counter[0] = 0u; }
    }
    const size_t NX = (size_t)N_ROWS * DIM;
    size_t e = (size_t)b * 1024 + (size_t)t * 4;
    const float* src; unsigned short* dst; float* sq; size_t off;
    if (e < NX) { src = x;  dst = xh; sq = xsq; off = e; }
    else        { src = cb; dst = ch; sq = csq; off = e - NX; }
    float4 v = *(const float4*)(src + off);
    ushort4 h;
    h.x = f2h(v.x); h.y = f2h(v.y); h.z = f2h(v.z); h.w = f2h(v.w);
    *(ushort4*)(dst + off) = h;
    double s = (double)v.x * v.x + (double)v.y * v.y
             + (double)v.z * v.z + (double)v.w * v.w;
    for (int o = 32; o; o >>= 1) s += __shfl_down(s, o);
    if ((t & 63) == 0) sq[off >> 8] = (float)s;
}

// ---- MFMA candidate GEMM. grid = (NRB, NCHUNK), 256 thr (4 waves).
// A panel persistent in regs; B via 4-buffer swizzled global_load_lds
// rotation with counted vmcnt (loads in flight across barriers).
__global__ __launch_bounds__(256, 2) void vq_gemm_kernel(
        const unsigned short* __restrict__ xh_g, const unsigned short* __restrict__ ch_g,
        const float* __restrict__ xsq, const float* __restrict__ csq,
        unsigned* __restrict__ colmin_part, uint2* __restrict__ top2_out) {
    __shared__ __align__(16) unsigned short b_lds[4][TN][BK];  // 32 KB
    __shared__ float    xsq_l[128];
    __shared__ unsigned colmin_l[KC];
    __shared__ uint2    u12_l[16][256];   // 32 KB: per-thread top-2 state

    const int t = threadIdx.x;
    const int wave = t >> 6, lane = t & 63, quad = lane >> 4, L = lane & 15;
    const int whalf = wave >> 1, chalf = wave & 1;
    const int row0  = blockIdx.x * TM;
    const int code0 = blockIdx.y * KC;

    if (t < 128) xsq_l[t] = xsq[row0 + t];
    colmin_l[t] = 0xFFFFFFFFu; colmin_l[t + 256] = 0xFFFFFFFFu;
#pragma unroll
    for (int i = 0; i < 16; ++i)
        u12_l[i][t] = make_uint2(0xFFFFFFFFu, 0xFFFFFFFFu);

    const unsigned short* abase =
        xh_g + ((size_t)(row0 + whalf * 64 + L) * DIM + quad * 8);

    // Staging (swizzled): LDS 16B-chunk j holds global (row j>>2,
    // slot (j&3)^((j>>3)&3)) -- slot t at row r carries global slot
    // t^((r>>1)&3), an involution. Linear LDS dest per DMA semantics.
    auto stageB = [&](int buf, int kt_, int dc_) {
        const unsigned short* bsrc =
            ch_g + (size_t)(code0 + kt_ * TN) * DIM + dc_ * BK;
        unsigned short* dst = &b_lds[buf][0][0];
#pragma unroll
        for (int k = 0; k < 2; ++k) {
            const int j = t + k * 256;
            const int r = j >> 2, sg = (j & 3) ^ ((j >> 3) & 3);
            GLOAD_LDS16(bsrc + (size_t)r * DIM + sg * 8, dst + (size_t)j * 8);
        }
    };

    const int bslot = (L >> 1) & 3;     // read-side swizzle term

    // ---- prologue (issue order matters for vmcnt accounting):
    // 1) A panel -> 32 persistent VGPR frags; 2) csq -> 16 regs;
    // 3) stages 0,1,2 (6 loads outstanding). vmcnt is issue-ordered, so
    // WAITVM(4) at step 0 drains A+csq+stage0, leaving stages 1,2.
    f16x8 afr[NDC][4];                  // 128 VGPRs, compile-time indexed
#pragma unroll
    for (int dc = 0; dc < NDC; ++dc)
#pragma unroll
        for (int mt = 0; mt < 4; ++mt)
            afr[dc][mt] = *(const f16x8*)(abase + (size_t)mt * 16 * DIM + dc * BK);
    float csq_r[NKT][4];                // 16 VGPRs, compile-time indexed
#pragma unroll
    for (int kt = 0; kt < NKT; ++kt)
#pragma unroll
        for (int nt = 0; nt < 4; ++nt)
            csq_r[kt][nt] = csq[code0 + kt * TN + chalf * 64 + nt * 16 + L];
    stageB(0, 0, 0);
    stageB(1, 0, 1);
    stageB(2, 0, 2);

#pragma unroll
    for (int kt = 0; kt < NKT; ++kt) {
        f32x4 acc[4][4];
#pragma unroll
        for (int mt = 0; mt < 4; ++mt)
#pragma unroll
            for (int nt = 0; nt < 4; ++nt) acc[mt][nt] = (f32x4){0.f, 0.f, 0.f, 0.f};

#pragma unroll
        for (int dc = 0; dc < NDC; ++dc) {
            const int s = kt * NDC + dc;       // compile-time (full unroll)
            // wait own stage(s) loads (leave later stages in flight)
            if (s < NSTEP - 2)      WAITVM(4);
            else if (s == NSTEP - 2) WAITVM(2);
            else                     WAITVM(0);
            __builtin_amdgcn_s_barrier();      // publish buf[s&3] to all
            __builtin_amdgcn_sched_barrier(0); // pin: nothing hoists above
            if (s + 3 < NSTEP)
                stageB((s + 3) & 3, (s + 3) >> 3, (s + 3) & 7);

            f16x8 bf[4];
#pragma unroll
            for (int nt = 0; nt < 4; ++nt)
                bf[nt] = *(const f16x8*)
                    &b_lds[s & 3][chalf * 64 + nt * 16 + L][(quad ^ bslot) * 8];
#pragma unroll
            for (int mt = 0; mt < 4; ++mt)
#pragma unroll
                for (int nt = 0; nt < 4; ++nt)
                    acc[mt][nt] = __builtin_amdgcn_mfma_f32_16x16x32_f16(
                        afr[dc][mt], bf[nt], acc[mt][nt], 0, 0, 0);
        }

        // ---- epilogue: packed-key top-2 upkeep (LDS state) + column-min.
        // Zero VMEM here (csq in regs) -- no pipeline re-drain; the next
        // 3 slices' DMAs fly under this ~1300cy VALU phase.
        unsigned colf[4];
        float dmin[4] = {3.4e38f, 3.4e38f, 3.4e38f, 3.4e38f};
#pragma unroll
        for (int nt = 0; nt < 4; ++nt)
            colf[nt] = (unsigned)(kt * 128 + chalf * 64 + nt * 16 + L);
#pragma unroll
        for (int mt = 0; mt < 4; ++mt) {
            const f32x4 xq = *(const f32x4*)&xsq_l[whalf * 64 + mt * 16 + quad * 4];
#pragma unroll
            for (int reg = 0; reg < 4; ++reg) {
                const int i = mt * 4 + reg;
                uint2 e = u12_l[i][t];
#pragma unroll
                for (int nt = 0; nt < 4; ++nt) {
                    float s = fmaf(-2.0f, acc[mt][nt][reg], csq_r[kt][nt]);
                    unsigned key = (fkey(s) & 0xFFFFFE00u) | colf[nt];
                    unsigned lo = umin_(e.x, key);
                    e.y = umin_(e.y, umax_(e.x, key));
                    e.x = lo;
                    dmin[nt] = fminf(dmin[nt], xq[reg] + s);
                }
                u12_l[i][t] = e;
            }
        }
#pragma unroll
        for (int nt = 0; nt < 4; ++nt) {
            unsigned dk = fkey(dmin[nt]);
            dk = umin_(dk, (unsigned)__shfl_xor((int)dk, 16));
            dk = umin_(dk, (unsigned)__shfl_xor((int)dk, 32));
            if (quad == 0)
                atomicMin(&colmin_l[kt * TN + chalf * 64 + nt * 16 + L], dk);
        }
    }

    // ---- once per block: butterfly-merge top-2 across the 16 L-lanes ----
    unsigned u1[16], u2[16];
#pragma unroll
    for (int i = 0; i < 16; ++i) {
        uint2 e = u12_l[i][t];
        u1[i] = e.x; u2[i] = e.y;
    }
#pragma unroll
    for (int i = 0; i < 16; ++i) {
#pragma unroll
        for (int st = 1; st < 16; st <<= 1) {
            unsigned w1 = (unsigned)__shfl_xor((int)u1[i], st);
            unsigned w2 = (unsigned)__shfl_xor((int)u2[i], st);
            unsigned a = umin_(u1[i], w1), b = umax_(u1[i], w1);
            u1[i] = a;
            u2[i] = umin_(umin_(u2[i], w2), b);
        }
    }
    if (L == 0) {
        const size_t gbase = (size_t)(blockIdx.y * 2 + chalf) * N_ROWS;
#pragma unroll
        for (int mt = 0; mt < 4; ++mt)
#pragma unroll
            for (int reg = 0; reg < 4; ++reg) {
                const int row = row0 + whalf * 64 + mt * 16 + quad * 4 + reg;
                top2_out[gbase + row] = make_uint2(u1[mt * 4 + reg], u2[mt * 4 + reg]);
            }
    }

    // ---- flush block-local colmin to private slice (plain stores) ----
    __syncthreads();
    unsigned* cp = colmin_part + (size_t)blockIdx.x * KCODES + code0;
    cp[t]       = colmin_l[t];
    cp[t + 256] = colmin_l[t + 256];
}

// ---- refine + gather + MSE, fused. grid = N_ROWS/4, 1 wave per row. ----
// R17: lane-parallel candidate selection. Lane l<32 owns candidate
// (granule l>>1, slot l&1) as u64 key (score32|id32) -- same ordering as
// the old (v,id) lexicographic ins8. Fast path: (min1,min2) butterfly.
// Slow path (rare): 8x extract-min recovers the identical top-8 set, then
// unchanged cooperative fp64 re-score + 0.75*ulp_fp32 tie rule.
__global__ __launch_bounds__(256) void vq_refine_kernel(
        const float* __restrict__ x, const float* __restrict__ cb,
        const uint2* __restrict__ top2, unsigned* __restrict__ active,
        float* __restrict__ out, double* __restrict__ accum) {
    __shared__ double wsum[4];
    const int wave = threadIdx.x >> 6, lane = threadIdx.x & 63;
    const int row  = blockIdx.x * 4 + wave;

    // lane-owned candidate -> packed u64 (quantized-score | id)
    const int g = (lane >> 1) & 15;
    uint2 e = top2[(size_t)g * N_ROWS + row];
    unsigned key = (lane & 1) ? e.y : e.x;
    unsigned idc = (unsigned)((g >> 1) * KC) + (key & 0x1FFu);
    unsigned long long pk =
        ((unsigned long long)(key & 0xFFFFFE00u) << 32) | idc;
    if (lane >= 32) pk = ~0ull;

    // butterfly (min1, min2) across 64 lanes -- wave-uniform result
    unsigned long long m1 = pk, m2 = ~0ull;
#pragma unroll
    for (int o = 1; o < 64; o <<= 1) {
        unsigned long long w1 = (unsigned long long)__shfl_xor((long long)m1, o);
        unsigned long long w2 = (unsigned long long)__shfl_xor((long long)m2, o);
        unsigned long long lo = umin64_(m1, w1), hi = umax64_(m1, w1);
        m1 = lo;
        m2 = umin64_(umin64_(m2, w2), hi);
    }
    const float v0 = fkey_inv((unsigned)(m1 >> 32));
    const float v1 = fkey_inv((unsigned)(m2 >> 32));

    float4 xv = ((const float4*)(x + (size_t)row * DIM))[lane];
    int tok;
    if (v1 > v0 + 1.0e-2f) {
        tok = (int)(unsigned)(m1 & 0xFFFFFFFFu);
    } else {
        // recover top-8 ids (ascending (v,id) order) by repeated extract-min
        int id8[8];
        unsigned long long cur = pk;
#pragma unroll
        for (int k = 0; k < 8; ++k) {
            unsigned long long m = cur;
#pragma unroll
            for (int o = 1; o < 64; o <<= 1)
                m = umin64_(m, (unsigned long long)__shfl_xor((long long)m, o));
            id8[k] = (int)(unsigned)(m & 0xFFFFFFFFu);
            if (cur == m) cur = ~0ull;   // owning lane removes it
        }

        double xs64 = (double)xv.x * xv.x + (double)xv.y * xv.y
                    + (double)xv.z * xv.z + (double)xv.w * xv.w;
        double dd[8], cc2[8];
#pragma unroll
        for (int k = 0; k < 8; ++k) {
            float4 c4 = ((const float4*)(cb + (size_t)id8[k] * DIM))[lane];
            dd[k]  = (double)xv.x * c4.x + (double)xv.y * c4.y
                   + (double)xv.z * c4.z + (double)xv.w * c4.w;
            cc2[k] = (double)c4.x * c4.x + (double)c4.y * c4.y
                   + (double)c4.z * c4.z + (double)c4.w * c4.w;
        }
#pragma unroll
        for (int o = 32; o; o >>= 1) {
            xs64 += __shfl_down(xs64, o);
#pragma unroll
            for (int k = 0; k < 8; ++k) {
                dd[k]  += __shfl_down(dd[k], o);
                cc2[k] += __shfl_down(cc2[k], o);
            }
        }
        if (lane == 0) {
            double D[8], Dmin = 1e300;
#pragma unroll
            for (int k = 0; k < 8; ++k) {
                D[k] = xs64 + cc2[k] - 2.0 * dd[k];
                Dmin = fmin(Dmin, D[k]);
            }
            int e2; frexp(Dmin, &e2);
            double U   = ldexp(1.0, e2 - 1 - 23);     // ulp_fp32(Dmin)
            double thr = Dmin + 0.75 * U;
            tok = 0x7FFFFFFF;
#pragma unroll
            for (int k = 0; k < 8; ++k)
                if (D[k] <= thr && id8[k] < tok) tok = id8[k];
        }
        tok = __shfl(tok, 0);
    }

    if (lane == 0) active[tok] = 1u;
    float4 sel = ((const float4*)(cb + (size_t)tok * DIM))[lane];
    ((float4*)out)[(size_t)row * 64 + lane] = sel;
    float dx = sel.x - xv.x, dy = sel.y - xv.y, dz = sel.z - xv.z, dw = sel.w - xv.w;
    float s = dx * dx + dy * dy + dz * dz + dw * dw;
    for (int o = 32; o; o >>= 1) s += __shfl_down(s, o);
    if (lane == 0) wsum[wave] = (double)s;
    __syncthreads();
    if (threadIdx.x == 0) atomicAdd(accum, wsum[0] + wsum[1] + wsum[2] + wsum[3]);
}

// ---- final: 128-way colmin reduction + entropy + loss. grid = 16 blocks.
// Each block reduces 256 codes over the 128 row-block partials, adds its
// inactive-code entropy partial; the 16th finisher computes the loss.
__global__ __launch_bounds__(256) void vq_final_kernel(
        const unsigned* __restrict__ colmin_part, const unsigned* __restrict__ active,
        double* __restrict__ accum, unsigned* __restrict__ counter,
        float* __restrict__ out) {
    __shared__ double red[256];
    const int t = threadIdx.x;
    const int c = blockIdx.x * 256 + t;
    unsigned m = 0xFFFFFFFFu;
#pragma unroll 8
    for (int rb = 0; rb < NRB; ++rb)
        m = umin_(m, colmin_part[(size_t)rb * KCODES + c]);
    red[t] = (active[c] == 0u) ? (double)fkey_inv(m) : 0.0;
    __syncthreads();
    for (int o = 128; o; o >>= 1) {
        if (t < o) red[t] += red[t + o];
        __syncthreads();
    }
    if (t == 0) {
        atomicAdd(&accum[1], red[0]);
        __threadfence();
        unsigned old = atomicAdd(counter, 1u);
        if (old == 15u) {
            __threadfence();
            double ent = atomicAdd(&accum[1], 0.0);   // atomic read
            double loss = 1.25 * (accum[0] / (double)((size_t)N_ROWS * DIM))
                        + 0.02 * (ent / (double)KCODES);
            out[(size_t)N_ROWS * DIM] = (float)loss;
        }
    }
}

extern "C" void kernel_launch(void* const* d_in, const int* in_sizes, int n_in,
                              void* d_out, int out_size, void* d_ws, size_t ws_size,
                              hipStream_t stream) {
    const float* x  = (const float*)d_in[0];   // [16384, 256]
    const float* cb = (const float*)d_in[1];   // [4096, 256]
    float* out = (float*)d_out;                // [16384*256] ++ [1] loss

    char* ws = (char*)d_ws;
    float*    xsq     = (float*)(ws + 0);                      // 64 KB
    float*    csq     = (float*)(ws + 65536);                  // 16 KB
    unsigned* active  = (unsigned*)(ws + 81920);               // 16 KB
    double*   accum   = (double*)(ws + 98304);                 // 256 B (mse, entropy)
    unsigned* counter = (unsigned*)(ws + 98560);               // 64 B
    uint2*    top2    = (uint2*)(ws + 131072);                 // 2 MB (16 granules)
    unsigned* cpart   = (unsigned*)(ws + 2228224);             // 2 MB (128 x 4096)
    unsigned short* xh_g = (unsigned short*)(ws + 4325376);    // 8 MB
    unsigned short* ch_g = (unsigned short*)(ws + 12713984);   // 2 MB (~14.2 MB)

    vq_prep_kernel<<<((N_ROWS + KCODES) * DIM) / 1024, 256, 0, stream>>>(
        x, cb, xh_g, ch_g, xsq, csq, active, accum, counter);
    vq_gemm_kernel<<<dim3(NRB, NCHUNK), 256, 0, stream>>>(
        xh_g, ch_g, xsq, csq, cpart, top2);
    vq_refine_kernel<<<N_ROWS / 4, 256, 0, stream>>>(
        x, cb, top2, active, out, accum);
    vq_final_kernel<<<KCODES / 256, 256, 0, stream>>>(
        cpart, active, accum, counter, out);
}

// Round 9
// 204.780 us; speedup vs baseline: 1.0409x; 1.0409x over previous
//
#include <hip/hip_runtime.h>
#include <stdint.h>

// ---------------------------------------------------------------------------
// VectorQuantizer: argmin_k ||x_n - c_k||^2 + straight-through out + losses.
//
// Token semantics (R4/R5/R7/R9-verified): candidates by continuous score
// s = ||c||^2 - 2 x.c via fp16 MFMA; exact fp64 re-score; token = lowest
// index within 0.75*ulp_fp32(Dmin) of the minimum.
//
// R15: swizzled global_load_lds dbuf B: gemm 103us. R16: A panel in 128
// VGPRs: gemm 74us. R17: lane-parallel refine: total 203us (best).
// R18 FAILED perf: counted-vmcnt via full unroll -> spill (WRITE 42MB).
// R19 FAILED correctness: dropped R18's sched_barrier(0) after s_barrier.
//   Raw s_barrier has no fence semantics -> hipcc hoisted ds_read(bf)
//   above the barrier; own WAITVM only covers own quarter-slice, other
//   waves' DMAs guaranteed only by THEIR pre-barrier WAITVM -> stale LDS.
// R20: R19 + deterministic ordering fixes only:
//   (a) sched_barrier(0) after EVERY s_barrier (R18's exact placement,
//       which passed correctness) -- pins ds_reads below the barrier.
//   (b) empty asm memory-clobber pins in the prologue (A-panel loads,
//       then each stageB in order) -- the WAITVM(4) accounting's issue
//       order is guaranteed, not scheduler luck.
//   Pipeline re-audited incl. per-kt epilogue vmcnt(0) drain (transient
//   csq): every read-target buffer is drained by its read step in all
//   interleavings; tail 4/2/0 verified; WAR barrier-protected.
// ---------------------------------------------------------------------------

#define N_ROWS 16384
#define DIM    256
#define KCODES 4096
#define NCHUNK 8
#define KC     (KCODES / NCHUNK)   // 512 codes per chunk
#define TM     128                 // rows per block tile
#define TN     128                 // codes per code-tile
#define BK     32                  // K per dc step
#define NKT    (KC / TN)           // 4 code tiles per chunk
#define NDC    (DIM / BK)          // 8 K-steps
#define NSTEP  (NKT * NDC)         // 32 pipeline steps
#define NGRAN  (NCHUNK * 2)        // 16 granules of 256 cols (chunk x chalf)
#define NRB    (N_ROWS / TM)       // 128 row-blocks

typedef float    f32x4 __attribute__((ext_vector_type(4)));
typedef _Float16 f16x8 __attribute__((ext_vector_type(8)));

#define GLOAD_LDS16(g, l) __builtin_amdgcn_global_load_lds(                 \
    (const __attribute__((address_space(1))) void*)(g),                     \
    (__attribute__((address_space(3))) void*)(l), 16, 0, 0)

#define WAITVM_(n) asm volatile("s_waitcnt vmcnt(" #n ")" ::: "memory")
#define WAITVM(n)  WAITVM_(n)
#define MEMPIN()   asm volatile("" ::: "memory")

__device__ __forceinline__ unsigned umin_(unsigned a, unsigned b) { return a < b ? a : b; }
__device__ __forceinline__ unsigned umax_(unsigned a, unsigned b) { return a > b ? a : b; }
__device__ __forceinline__ unsigned long long umin64_(unsigned long long a,
                                                      unsigned long long b) {
    return a < b ? a : b;
}
__device__ __forceinline__ unsigned long long umax64_(unsigned long long a,
                                                      unsigned long long b) {
    return a > b ? a : b;
}

// order-preserving float->uint key
__device__ __forceinline__ unsigned fkey(float f) {
    unsigned b = __float_as_uint(f);
    return (b & 0x80000000u) ? ~b : (b | 0x80000000u);
}
__device__ __forceinline__ float fkey_inv(unsigned k) {
    unsigned b = (k & 0x80000000u) ? (k ^ 0x80000000u) : ~k;
    return __uint_as_float(b);
}
__device__ __forceinline__ unsigned short f2h(float f) {
    union { _Float16 h; unsigned short u; } cv;
    cv.h = (_Float16)f;            // v_cvt_f16_f32, RNE
    return cv.u;
}

// ---- prep: fp16 cast + row sumsq (fp64->fp32) + buffer init, fused ----
__global__ __launch_bounds__(256) void vq_prep_kernel(
        const float* __restrict__ x, const float* __restrict__ cb,
        unsigned short* __restrict__ xh, unsigned short* __restrict__ ch,
        float* __restrict__ xsq, float* __restrict__ csq,
        unsigned* __restrict__ active, double* __restrict__ accum,
        unsigned* __restrict__ counter) {
    const int b = blockIdx.x, t = threadIdx.x;
    if (b < KCODES / 256) {
        int i = b * 256 + t;
        active[i] = 0u;
        if (i == 0) { accum[0] = 0.0; accum[1] = 0.0; counter[0] = 0u; }
    }
    const size_t NX = (size_t)N_ROWS * DIM;
    size_t e = (size_t)b * 1024 + (size_t)t * 4;
    const float* src; unsigned short* dst; float* sq; size_t off;
    if (e < NX) { src = x;  dst = xh; sq = xsq; off = e; }
    else        { src = cb; dst = ch; sq = csq; off = e - NX; }
    float4 v = *(const float4*)(src + off);
    ushort4 h;
    h.x = f2h(v.x); h.y = f2h(v.y); h.z = f2h(v.z); h.w = f2h(v.w);
    *(ushort4*)(dst + off) = h;
    double s = (double)v.x * v.x + (double)v.y * v.y
             + (double)v.z * v.z + (double)v.w * v.w;
    for (int o = 32; o; o >>= 1) s += __shfl_down(s, o);
    if ((t & 63) == 0) sq[off >> 8] = (float)s;
}

// ---- MFMA candidate GEMM. grid = (NRB, NCHUNK), 256 thr (4 waves).
// A panel persistent in regs; B via 4-buffer swizzled global_load_lds
// rotation; counted vmcnt (loads in flight across barriers), dynamic kt.
__global__ __launch_bounds__(256, 2) void vq_gemm_kernel(
        const unsigned short* __restrict__ xh_g, const unsigned short* __restrict__ ch_g,
        const float* __restrict__ xsq, const float* __restrict__ csq,
        unsigned* __restrict__ colmin_part, uint2* __restrict__ top2_out) {
    __shared__ __align__(16) unsigned short b_lds[4][TN][BK];  // 32 KB
    __shared__ float    xsq_l[128];
    __shared__ unsigned colmin_l[KC];
    __shared__ uint2    u12_l[16][256];   // 32 KB: per-thread top-2 state

    const int t = threadIdx.x;
    const int wave = t >> 6, lane = t & 63, quad = lane >> 4, L = lane & 15;
    const int whalf = wave >> 1, chalf = wave & 1;
    const int row0  = blockIdx.x * TM;
    const int code0 = blockIdx.y * KC;

    if (t < 128) xsq_l[t] = xsq[row0 + t];
    colmin_l[t] = 0xFFFFFFFFu; colmin_l[t + 256] = 0xFFFFFFFFu;
#pragma unroll
    for (int i = 0; i < 16; ++i)
        u12_l[i][t] = make_uint2(0xFFFFFFFFu, 0xFFFFFFFFu);

    const unsigned short* abase =
        xh_g + ((size_t)(row0 + whalf * 64 + L) * DIM + quad * 8);

    // Staging (swizzled): LDS 16B-chunk j holds global (row j>>2,
    // slot (j&3)^((j>>3)&3)) -- slot t at row r carries global slot
    // t^((r>>1)&3), an involution. Linear LDS dest per DMA semantics.
    auto stageB = [&](int buf, int kt_, int dc_) {
        const unsigned short* bsrc =
            ch_g + (size_t)(code0 + kt_ * TN) * DIM + dc_ * BK;
        unsigned short* dst = &b_lds[buf][0][0];
#pragma unroll
        for (int k = 0; k < 2; ++k) {
            const int j = t + k * 256;
            const int r = j >> 2, sg = (j & 3) ^ ((j >> 3) & 3);
            GLOAD_LDS16(bsrc + (size_t)r * DIM + sg * 8, dst + (size_t)j * 8);
        }
    };

    const int bslot = (L >> 1) & 3;     // read-side swizzle term

    // ---- prologue: A panel -> 32 persistent VGPR frags; stages 0,1,2.
    // MEMPIN between groups: WAITVM accounting requires this issue order.
    f16x8 afr[NDC][4];                  // 128 VGPRs, compile-time indexed
#pragma unroll
    for (int dc = 0; dc < NDC; ++dc)
#pragma unroll
        for (int mt = 0; mt < 4; ++mt)
            afr[dc][mt] = *(const f16x8*)(abase + (size_t)mt * 16 * DIM + dc * BK);
    MEMPIN();
    stageB(0, 0, 0);
    MEMPIN();
    stageB(1, 0, 1);
    MEMPIN();
    stageB(2, 0, 2);
    MEMPIN();

    // publish LDS init without draining the staged DMAs
    asm volatile("s_waitcnt lgkmcnt(0)" ::: "memory");
    __builtin_amdgcn_s_barrier();
    __builtin_amdgcn_sched_barrier(0);

    // epilogue (per kt): packed-key top-2 upkeep + column-min. csq loaded
    // transiently (compiler's vmcnt wait re-drains once per kt, covered
    // by this ~1300cy VALU phase; drain only tightens the pipeline waits).
    auto epilogue = [&](int kt, f32x4 (&acc)[4][4]) {
        float csq4[4]; unsigned colf[4];
        float dmin[4] = {3.4e38f, 3.4e38f, 3.4e38f, 3.4e38f};
#pragma unroll
        for (int nt = 0; nt < 4; ++nt) {
            csq4[nt] = csq[code0 + kt * TN + chalf * 64 + nt * 16 + L];
            colf[nt] = (unsigned)(kt * 128 + chalf * 64 + nt * 16 + L);
        }
#pragma unroll
        for (int mt = 0; mt < 4; ++mt) {
            const f32x4 xq = *(const f32x4*)&xsq_l[whalf * 64 + mt * 16 + quad * 4];
#pragma unroll
            for (int reg = 0; reg < 4; ++reg) {
                const int i = mt * 4 + reg;
                uint2 e = u12_l[i][t];
#pragma unroll
                for (int nt = 0; nt < 4; ++nt) {
                    float s = fmaf(-2.0f, acc[mt][nt][reg], csq4[nt]);
                    unsigned key = (fkey(s) & 0xFFFFFE00u) | colf[nt];
                    unsigned lo = umin_(e.x, key);
                    e.y = umin_(e.y, umax_(e.x, key));
                    e.x = lo;
                    dmin[nt] = fminf(dmin[nt], xq[reg] + s);
                }
                u12_l[i][t] = e;
            }
        }
#pragma unroll
        for (int nt = 0; nt < 4; ++nt) {
            unsigned dk = fkey(dmin[nt]);
            dk = umin_(dk, (unsigned)__shfl_xor((int)dk, 16));
            dk = umin_(dk, (unsigned)__shfl_xor((int)dk, 32));
            if (quad == 0)
                atomicMin(&colmin_l[kt * TN + chalf * 64 + nt * 16 + L], dk);
        }
    };

    // ---- main kts (dynamic loop; all steps stage, all WAITVM(4)) ----
    for (int kt = 0; kt < NKT - 1; ++kt) {
        f32x4 acc[4][4];
#pragma unroll
        for (int mt = 0; mt < 4; ++mt)
#pragma unroll
            for (int nt = 0; nt < 4; ++nt) acc[mt][nt] = (f32x4){0.f, 0.f, 0.f, 0.f};
#pragma unroll
        for (int dc = 0; dc < NDC; ++dc) {
            WAITVM(4);                       // own stage(s) landed
            __builtin_amdgcn_s_barrier();    // publish buf[dc&3]
            __builtin_amdgcn_sched_barrier(0);  // pin ds_reads below barrier
            stageB((dc + 3) & 3, kt + (dc >= 5), (dc + 3) & 7);
            f16x8 bf[4];
#pragma unroll
            for (int nt = 0; nt < 4; ++nt)
                bf[nt] = *(const f16x8*)
                    &b_lds[dc & 3][chalf * 64 + nt * 16 + L][(quad ^ bslot) * 8];
#pragma unroll
            for (int mt = 0; mt < 4; ++mt)
#pragma unroll
                for (int nt = 0; nt < 4; ++nt)
                    acc[mt][nt] = __builtin_amdgcn_mfma_f32_16x16x32_f16(
                        afr[dc][mt], bf[nt], acc[mt][nt], 0, 0, 0);
        }
        epilogue(kt, acc);
    }

    // ---- peeled last kt (tail vmcnt 4/2/0; stages only while s+3<NSTEP) --
    {
        const int kt = NKT - 1;
        f32x4 acc[4][4];
#pragma unroll
        for (int mt = 0; mt < 4; ++mt)
#pragma unroll
            for (int nt = 0; nt < 4; ++nt) acc[mt][nt] = (f32x4){0.f, 0.f, 0.f, 0.f};
#pragma unroll
        for (int dc = 0; dc < NDC; ++dc) {
            if (dc <= 5)      WAITVM(4);
            else if (dc == 6) WAITVM(2);
            else              WAITVM(0);
            __builtin_amdgcn_s_barrier();
            __builtin_amdgcn_sched_barrier(0);  // pin ds_reads below barrier
            if (dc <= 4)
                stageB((dc + 3) & 3, kt, (dc + 3) & 7);
            f16x8 bf[4];
#pragma unroll
            for (int nt = 0; nt < 4; ++nt)
                bf[nt] = *(const f16x8*)
                    &b_lds[dc & 3][chalf * 64 + nt * 16 + L][(quad ^ bslot) * 8];
#pragma unroll
            for (int mt = 0; mt < 4; ++mt)
#pragma unroll
                for (int nt = 0; nt < 4; ++nt)
                    acc[mt][nt] = __builtin_amdgcn_mfma_f32_16x16x32_f16(
                        afr[dc][mt], bf[nt], acc[mt][nt], 0, 0, 0);
        }
        epilogue(kt, acc);
    }

    // ---- once per block: butterfly-merge top-2 across the 16 L-lanes ----
    unsigned u1[16], u2[16];
#pragma unroll
    for (int i = 0; i < 16; ++i) {
        uint2 e = u12_l[i][t];
        u1[i] = e.x; u2[i] = e.y;
    }
#pragma unroll
    for (int i = 0; i < 16; ++i) {
#pragma unroll
        for (int st = 1; st < 16; st <<= 1) {
            unsigned w1 = (unsigned)__shfl_xor((int)u1[i], st);
            unsigned w2 = (unsigned)__shfl_xor((int)u2[i], st);
            unsigned a = umin_(u1[i], w1), b = umax_(u1[i], w1);
            u1[i] = a;
            u2[i] = umin_(umin_(u2[i], w2), b);
        }
    }
    if (L == 0) {
        const size_t gbase = (size_t)(blockIdx.y * 2 + chalf) * N_ROWS;
#pragma unroll
        for (int mt = 0; mt < 4; ++mt)
#pragma unroll
            for (int reg = 0; reg < 4; ++reg) {
                const int row = row0 + whalf * 64 + mt * 16 + quad * 4 + reg;
                top2_out[gbase + row] = make_uint2(u1[mt * 4 + reg], u2[mt * 4 + reg]);
            }
    }

    // ---- flush block-local colmin to private slice (plain stores) ----
    __syncthreads();
    unsigned* cp = colmin_part + (size_t)blockIdx.x * KCODES + code0;
    cp[t]       = colmin_l[t];
    cp[t + 256] = colmin_l[t + 256];
}

// ---- refine + gather + MSE, fused. grid = N_ROWS/4, 1 wave per row. ----
// R17: lane-parallel candidate selection. Lane l<32 owns candidate
// (granule l>>1, slot l&1) as u64 key (score32|id32) -- same ordering as
// the old (v,id) lexicographic ins8. Fast path: (min1,min2) butterfly.
// Slow path (rare): 8x extract-min recovers the identical top-8 set, then
// unchanged cooperative fp64 re-score + 0.75*ulp_fp32 tie rule.
__global__ __launch_bounds__(256) void vq_refine_kernel(
        const float* __restrict__ x, const float* __restrict__ cb,
        const uint2* __restrict__ top2, unsigned* __restrict__ active,
        float* __restrict__ out, double* __restrict__ accum) {
    __shared__ double wsum[4];
    const int wave = threadIdx.x >> 6, lane = threadIdx.x & 63;
    const int row  = blockIdx.x * 4 + wave;

    // lane-owned candidate -> packed u64 (quantized-score | id)
    const int g = (lane >> 1) & 15;
    uint2 e = top2[(size_t)g * N_ROWS + row];
    unsigned key = (lane & 1) ? e.y : e.x;
    unsigned idc = (unsigned)((g >> 1) * KC) + (key & 0x1FFu);
    unsigned long long pk =
        ((unsigned long long)(key & 0xFFFFFE00u) << 32) | idc;
    if (lane >= 32) pk = ~0ull;

    // butterfly (min1, min2) across 64 lanes -- wave-uniform result
    unsigned long long m1 = pk, m2 = ~0ull;
#pragma unroll
    for (int o = 1; o < 64; o <<= 1) {
        unsigned long long w1 = (unsigned long long)__shfl_xor((long long)m1, o);
        unsigned long long w2 = (unsigned long long)__shfl_xor((long long)m2, o);
        unsigned long long lo = umin64_(m1, w1), hi = umax64_(m1, w1);
        m1 = lo;
        m2 = umin64_(umin64_(m2, w2), hi);
    }
    const float v0 = fkey_inv((unsigned)(m1 >> 32));
    const float v1 = fkey_inv((unsigned)(m2 >> 32));

    float4 xv = ((const float4*)(x + (size_t)row * DIM))[lane];
    int tok;
    if (v1 > v0 + 1.0e-2f) {
        tok = (int)(unsigned)(m1 & 0xFFFFFFFFu);
    } else {
        // recover top-8 ids (ascending (v,id) order) by repeated extract-min
        int id8[8];
        unsigned long long cur = pk;
#pragma unroll
        for (int k = 0; k < 8; ++k) {
            unsigned long long m = cur;
#pragma unroll
            for (int o = 1; o < 64; o <<= 1)
                m = umin64_(m, (unsigned long long)__shfl_xor((long long)m, o));
            id8[k] = (int)(unsigned)(m & 0xFFFFFFFFu);
            if (cur == m) cur = ~0ull;   // owning lane removes it
        }

        double xs64 = (double)xv.x * xv.x + (double)xv.y * xv.y
                    + (double)xv.z * xv.z + (double)xv.w * xv.w;
        double dd[8], cc2[8];
#pragma unroll
        for (int k = 0; k < 8; ++k) {
            float4 c4 = ((const float4*)(cb + (size_t)id8[k] * DIM))[lane];
            dd[k]  = (double)xv.x * c4.x + (double)xv.y * c4.y
                   + (double)xv.z * c4.z + (double)xv.w * c4.w;
            cc2[k] = (double)c4.x * c4.x + (double)c4.y * c4.y
                   + (double)c4.z * c4.z + (double)c4.w * c4.w;
        }
#pragma unroll
        for (int o = 32; o; o >>= 1) {
            xs64 += __shfl_down(xs64, o);
#pragma unroll
            for (int k = 0; k < 8; ++k) {
                dd[k]  += __shfl_down(dd[k], o);
                cc2[k] += __shfl_down(cc2[k], o);
            }
        }
        if (lane == 0) {
            double D[8], Dmin = 1e300;
#pragma unroll
            for (int k = 0; k < 8; ++k) {
                D[k] = xs64 + cc2[k] - 2.0 * dd[k];
                Dmin = fmin(Dmin, D[k]);
            }
            int e2; frexp(Dmin, &e2);
            double U   = ldexp(1.0, e2 - 1 - 23);     // ulp_fp32(Dmin)
            double thr = Dmin + 0.75 * U;
            tok = 0x7FFFFFFF;
#pragma unroll
            for (int k = 0; k < 8; ++k)
                if (D[k] <= thr && id8[k] < tok) tok = id8[k];
        }
        tok = __shfl(tok, 0);
    }

    if (lane == 0) active[tok] = 1u;
    float4 sel = ((const float4*)(cb + (size_t)tok * DIM))[lane];
    ((float4*)out)[(size_t)row * 64 + lane] = sel;
    float dx = sel.x - xv.x, dy = sel.y - xv.y, dz = sel.z - xv.z, dw = sel.w - xv.w;
    float s = dx * dx + dy * dy + dz * dz + dw * dw;
    for (int o = 32; o; o >>= 1) s += __shfl_down(s, o);
    if (lane == 0) wsum[wave] = (double)s;
    __syncthreads();
    if (threadIdx.x == 0) atomicAdd(accum, wsum[0] + wsum[1] + wsum[2] + wsum[3]);
}

// ---- final: 128-way colmin reduction + entropy + loss. grid = 16 blocks.
// Each block reduces 256 codes over the 128 row-block partials, adds its
// inactive-code entropy partial; the 16th finisher computes the loss.
__global__ __launch_bounds__(256) void vq_final_kernel(
        const unsigned* __restrict__ colmin_part, const unsigned* __restrict__ active,
        double* __restrict__ accum, unsigned* __restrict__ counter,
        float* __restrict__ out) {
    __shared__ double red[256];
    const int t = threadIdx.x;
    const int c = blockIdx.x * 256 + t;
    unsigned m = 0xFFFFFFFFu;
#pragma unroll 8
    for (int rb = 0; rb < NRB; ++rb)
        m = umin_(m, colmin_part[(size_t)rb * KCODES + c]);
    red[t] = (active[c] == 0u) ? (double)fkey_inv(m) : 0.0;
    __syncthreads();
    for (int o = 128; o; o >>= 1) {
        if (t < o) red[t] += red[t + o];
        __syncthreads();
    }
    if (t == 0) {
        atomicAdd(&accum[1], red[0]);
        __threadfence();
        unsigned old = atomicAdd(counter, 1u);
        if (old == 15u) {
            __threadfence();
            double ent = atomicAdd(&accum[1], 0.0);   // atomic read
            double loss = 1.25 * (accum[0] / (double)((size_t)N_ROWS * DIM))
                        + 0.02 * (ent / (double)KCODES);
            out[(size_t)N_ROWS * DIM] = (float)loss;
        }
    }
}

extern "C" void kernel_launch(void* const* d_in, const int* in_sizes, int n_in,
                              void* d_out, int out_size, void* d_ws, size_t ws_size,
                              hipStream_t stream) {
    const float* x  = (const float*)d_in[0];   // [16384, 256]
    const float* cb = (const float*)d_in[1];   // [4096, 256]
    float* out = (float*)d_out;                // [16384*256] ++ [1] loss

    char* ws = (char*)d_ws;
    float*    xsq     = (float*)(ws + 0);                      // 64 KB
    float*    csq     = (float*)(ws + 65536);                  // 16 KB
    unsigned* active  = (unsigned*)(ws + 81920);               // 16 KB
    double*   accum   = (double*)(ws + 98304);                 // 256 B (mse, entropy)
    unsigned* counter = (unsigned*)(ws + 98560);               // 64 B
    uint2*    top2    = (uint2*)(ws + 131072);                 // 2 MB (16 granules)
    unsigned* cpart   = (unsigned*)(ws + 2228224);             // 2 MB (128 x 4096)
    unsigned short* xh_g = (unsigned short*)(ws + 4325376);    // 8 MB
    unsigned short* ch_g = (unsigned short*)(ws + 12713984);   // 2 MB (~14.2 MB)

    vq_prep_kernel<<<((N_ROWS + KCODES) * DIM) / 1024, 256, 0, stream>>>(
        x, cb, xh_g, ch_g, xsq, csq, active, accum, counter);
    vq_gemm_kernel<<<dim3(NRB, NCHUNK), 256, 0, stream>>>(
        xh_g, ch_g, xsq, csq, cpart, top2);
    vq_refine_kernel<<<N_ROWS / 4, 256, 0, stream>>>(
        x, cb, top2, active, out, accum);
    vq_final_kernel<<<KCODES / 256, 256, 0, stream>>>(
        cpart, active, accum, counter, out);
}

// Round 10
// 204.031 us; speedup vs baseline: 1.0447x; 1.0037x over previous
//
#include <hip/hip_runtime.h>
#include <stdint.h>

// ---------------------------------------------------------------------------
// VectorQuantizer: argmin_k ||x_n - c_k||^2 + straight-through out + losses.
//
// Token semantics (R4/R5/R7/R9-verified): candidates by continuous score
// s = ||c||^2 - 2 x.c via fp16 MFMA; exact fp64 re-score; token = lowest
// index within 0.75*ulp_fp32(Dmin) of the minimum.
//
// R15: swizzled global_load_lds dbuf B (103us). R16: A panel in 128 VGPRs
// (74us). R17: lane-parallel refine (total 203us). R18 FAILED perf (full
// unroll -> spill). R19 FAILED correctness (missing sched_barrier(0) after
// raw s_barrier -> ds_read hoisted above barrier). R20: fences fixed,
// passed, 75us gemm -- but peeled tail re-added ~11dw/thread spill (WRITE
// 17.4MB) and the epilogue's transient csq loads forced vmcnt(0) drains
// (in-order retirement: waiting for newest loads drains older stages).
// R21: drain-free + spill-free counted pipeline:
//   (a) csq -> LDS (csq_l[512], +2KB): epilogue is lgkm-only, zero VMEM,
//       no kt-boundary drains.
//   (b) no peel: uniform kt loop, wrap-around staging (ktn=(kt+(dc>=5))&3;
//       steps 29-31 stage dead slices into already-consumed buffers; WAR
//       barrier-protected identically to steady state). One loop body,
//       one epilogue instantiation -> spill source gone. Every step:
//       WAITVM(4); s_barrier; sched_barrier(0); stage; ds_read; 16 MFMA.
//   (c) refine slow path: per-lane p[k]=cc2-2dd partials -> 9-value fp64
//       reduce (was 17). Reassoc error ~2^-50*D << 0.75*ulp_fp32 rule.
// ---------------------------------------------------------------------------

#define N_ROWS 16384
#define DIM    256
#define KCODES 4096
#define NCHUNK 8
#define KC     (KCODES / NCHUNK)   // 512 codes per chunk
#define TM     128                 // rows per block tile
#define TN     128                 // codes per code-tile
#define BK     32                  // K per dc step
#define NKT    (KC / TN)           // 4 code tiles per chunk
#define NDC    (DIM / BK)          // 8 K-steps
#define NSTEP  (NKT * NDC)         // 32 pipeline steps
#define NGRAN  (NCHUNK * 2)        // 16 granules of 256 cols (chunk x chalf)
#define NRB    (N_ROWS / TM)       // 128 row-blocks

typedef float    f32x4 __attribute__((ext_vector_type(4)));
typedef _Float16 f16x8 __attribute__((ext_vector_type(8)));

#define GLOAD_LDS16(g, l) __builtin_amdgcn_global_load_lds(                 \
    (const __attribute__((address_space(1))) void*)(g),                     \
    (__attribute__((address_space(3))) void*)(l), 16, 0, 0)

#define WAITVM_(n) asm volatile("s_waitcnt vmcnt(" #n ")" ::: "memory")
#define WAITVM(n)  WAITVM_(n)
#define MEMPIN()   asm volatile("" ::: "memory")

__device__ __forceinline__ unsigned umin_(unsigned a, unsigned b) { return a < b ? a : b; }
__device__ __forceinline__ unsigned umax_(unsigned a, unsigned b) { return a > b ? a : b; }
__device__ __forceinline__ unsigned long long umin64_(unsigned long long a,
                                                      unsigned long long b) {
    return a < b ? a : b;
}
__device__ __forceinline__ unsigned long long umax64_(unsigned long long a,
                                                      unsigned long long b) {
    return a > b ? a : b;
}

// order-preserving float->uint key
__device__ __forceinline__ unsigned fkey(float f) {
    unsigned b = __float_as_uint(f);
    return (b & 0x80000000u) ? ~b : (b | 0x80000000u);
}
__device__ __forceinline__ float fkey_inv(unsigned k) {
    unsigned b = (k & 0x80000000u) ? (k ^ 0x80000000u) : ~k;
    return __uint_as_float(b);
}
__device__ __forceinline__ unsigned short f2h(float f) {
    union { _Float16 h; unsigned short u; } cv;
    cv.h = (_Float16)f;            // v_cvt_f16_f32, RNE
    return cv.u;
}

// ---- prep: fp16 cast + row sumsq (fp64->fp32) + buffer init, fused ----
__global__ __launch_bounds__(256) void vq_prep_kernel(
        const float* __restrict__ x, const float* __restrict__ cb,
        unsigned short* __restrict__ xh, unsigned short* __restrict__ ch,
        float* __restrict__ xsq, float* __restrict__ csq,
        unsigned* __restrict__ active, double* __restrict__ accum,
        unsigned* __restrict__ counter) {
    const int b = blockIdx.x, t = threadIdx.x;
    if (b < KCODES / 256) {
        int i = b * 256 + t;
        active[i] = 0u;
        if (i == 0) { accum[0] = 0.0; accum[1] = 0.0; counter[0] = 0u; }
    }
    const size_t NX = (size_t)N_ROWS * DIM;
    size_t e = (size_t)b * 1024 + (size_t)t * 4;
    const float* src; unsigned short* dst; float* sq; size_t off;
    if (e < NX) { src = x;  dst = xh; sq = xsq; off = e; }
    else        { src = cb; dst = ch; sq = csq; off = e - NX; }
    float4 v = *(const float4*)(src + off);
    ushort4 h;
    h.x = f2h(v.x); h.y = f2h(v.y); h.z = f2h(v.z); h.w = f2h(v.w);
    *(ushort4*)(dst + off) = h;
    double s = (double)v.x * v.x + (double)v.y * v.y
             + (double)v.z * v.z + (double)v.w * v.w;
    for (int o = 32; o; o >>= 1) s += __shfl_down(s, o);
    if ((t & 63) == 0) sq[off >> 8] = (float)s;
}

// ---- MFMA candidate GEMM. grid = (NRB, NCHUNK), 256 thr (4 waves).
// A panel persistent in regs; B via 4-buffer swizzled global_load_lds
// rotation; uniform counted-vmcnt pipeline (no peel, no epilogue VMEM).
__global__ __launch_bounds__(256, 2) void vq_gemm_kernel(
        const unsigned short* __restrict__ xh_g, const unsigned short* __restrict__ ch_g,
        const float* __restrict__ xsq, const float* __restrict__ csq,
        unsigned* __restrict__ colmin_part, uint2* __restrict__ top2_out) {
    __shared__ __align__(16) unsigned short b_lds[4][TN][BK];  // 32 KB
    __shared__ float    xsq_l[128];
    __shared__ float    csq_l[KC];        // 2 KB: epilogue is lgkm-only
    __shared__ unsigned colmin_l[KC];
    __shared__ uint2    u12_l[16][256];   // 32 KB: per-thread top-2 state

    const int t = threadIdx.x;
    const int wave = t >> 6, lane = t & 63, quad = lane >> 4, L = lane & 15;
    const int whalf = wave >> 1, chalf = wave & 1;
    const int row0  = blockIdx.x * TM;
    const int code0 = blockIdx.y * KC;

    if (t < 128) xsq_l[t] = xsq[row0 + t];
    csq_l[t]       = csq[code0 + t];
    csq_l[t + 256] = csq[code0 + t + 256];
    colmin_l[t] = 0xFFFFFFFFu; colmin_l[t + 256] = 0xFFFFFFFFu;
#pragma unroll
    for (int i = 0; i < 16; ++i)
        u12_l[i][t] = make_uint2(0xFFFFFFFFu, 0xFFFFFFFFu);

    const unsigned short* abase =
        xh_g + ((size_t)(row0 + whalf * 64 + L) * DIM + quad * 8);

    // Staging (swizzled): LDS 16B-chunk j holds global (row j>>2,
    // slot (j&3)^((j>>3)&3)) -- slot t at row r carries global slot
    // t^((r>>1)&3), an involution. Linear LDS dest per DMA semantics.
    auto stageB = [&](int buf, int kt_, int dc_) {
        const unsigned short* bsrc =
            ch_g + (size_t)(code0 + kt_ * TN) * DIM + dc_ * BK;
        unsigned short* dst = &b_lds[buf][0][0];
#pragma unroll
        for (int k = 0; k < 2; ++k) {
            const int j = t + k * 256;
            const int r = j >> 2, sg = (j & 3) ^ ((j >> 3) & 3);
            GLOAD_LDS16(bsrc + (size_t)r * DIM + sg * 8, dst + (size_t)j * 8);
        }
    };

    const int bslot = (L >> 1) & 3;     // read-side swizzle term

    // ---- prologue: A panel -> 32 persistent VGPR frags; stages 0,1,2.
    // MEMPIN between groups: WAITVM accounting requires this issue order.
    f16x8 afr[NDC][4];                  // 128 VGPRs, compile-time indexed
#pragma unroll
    for (int dc = 0; dc < NDC; ++dc)
#pragma unroll
        for (int mt = 0; mt < 4; ++mt)
            afr[dc][mt] = *(const f16x8*)(abase + (size_t)mt * 16 * DIM + dc * BK);
    MEMPIN();
    stageB(0, 0, 0);
    MEMPIN();
    stageB(1, 0, 1);
    MEMPIN();
    stageB(2, 0, 2);
    MEMPIN();

    // publish LDS init without draining the staged DMAs
    asm volatile("s_waitcnt lgkmcnt(0)" ::: "memory");
    __builtin_amdgcn_s_barrier();
    __builtin_amdgcn_sched_barrier(0);

    // epilogue (per kt): packed-key top-2 upkeep + column-min. All inputs
    // in LDS/regs -- zero VMEM, so no vmcnt drain inside the pipeline.
    auto epilogue = [&](int kt, f32x4 (&acc)[4][4]) {
        float csq4[4]; unsigned colf[4];
        float dmin[4] = {3.4e38f, 3.4e38f, 3.4e38f, 3.4e38f};
#pragma unroll
        for (int nt = 0; nt < 4; ++nt) {
            csq4[nt] = csq_l[kt * TN + chalf * 64 + nt * 16 + L];
            colf[nt] = (unsigned)(kt * 128 + chalf * 64 + nt * 16 + L);
        }
#pragma unroll
        for (int mt = 0; mt < 4; ++mt) {
            const f32x4 xq = *(const f32x4*)&xsq_l[whalf * 64 + mt * 16 + quad * 4];
#pragma unroll
            for (int reg = 0; reg < 4; ++reg) {
                const int i = mt * 4 + reg;
                uint2 e = u12_l[i][t];
#pragma unroll
                for (int nt = 0; nt < 4; ++nt) {
                    float s = fmaf(-2.0f, acc[mt][nt][reg], csq4[nt]);
                    unsigned key = (fkey(s) & 0xFFFFFE00u) | colf[nt];
                    unsigned lo = umin_(e.x, key);
                    e.y = umin_(e.y, umax_(e.x, key));
                    e.x = lo;
                    dmin[nt] = fminf(dmin[nt], xq[reg] + s);
                }
                u12_l[i][t] = e;
            }
        }
#pragma unroll
        for (int nt = 0; nt < 4; ++nt) {
            unsigned dk = fkey(dmin[nt]);
            dk = umin_(dk, (unsigned)__shfl_xor((int)dk, 16));
            dk = umin_(dk, (unsigned)__shfl_xor((int)dk, 32));
            if (quad == 0)
                atomicMin(&colmin_l[kt * TN + chalf * 64 + nt * 16 + L], dk);
        }
    };

    // ---- uniform main loop: every step WAITVM(4)+barrier+stage.
    // Steps 29-31 stage wrapped (dead) slices into buffers whose last
    // readers finished before the step's barrier -- WAR-safe, never read.
    for (int kt = 0; kt < NKT; ++kt) {
        f32x4 acc[4][4];
#pragma unroll
        for (int mt = 0; mt < 4; ++mt)
#pragma unroll
            for (int nt = 0; nt < 4; ++nt) acc[mt][nt] = (f32x4){0.f, 0.f, 0.f, 0.f};
#pragma unroll
        for (int dc = 0; dc < NDC; ++dc) {
            WAITVM(4);                       // stage (s-3) landed
            __builtin_amdgcn_s_barrier();    // publish buf[dc&3]
            __builtin_amdgcn_sched_barrier(0);  // pin ds_reads below barrier
            stageB((dc + 3) & 3, (kt + (dc >= 5)) & 3, (dc + 3) & 7);
            f16x8 bf[4];
#pragma unroll
            for (int nt = 0; nt < 4; ++nt)
                bf[nt] = *(const f16x8*)
                    &b_lds[dc & 3][chalf * 64 + nt * 16 + L][(quad ^ bslot) * 8];
#pragma unroll
            for (int mt = 0; mt < 4; ++mt)
#pragma unroll
                for (int nt = 0; nt < 4; ++nt)
                    acc[mt][nt] = __builtin_amdgcn_mfma_f32_16x16x32_f16(
                        afr[dc][mt], bf[nt], acc[mt][nt], 0, 0, 0);
        }
        epilogue(kt, acc);
    }

    // ---- once per block: butterfly-merge top-2 across the 16 L-lanes ----
    unsigned u1[16], u2[16];
#pragma unroll
    for (int i = 0; i < 16; ++i) {
        uint2 e = u12_l[i][t];
        u1[i] = e.x; u2[i] = e.y;
    }
#pragma unroll
    for (int i = 0; i < 16; ++i) {
#pragma unroll
        for (int st = 1; st < 16; st <<= 1) {
            unsigned w1 = (unsigned)__shfl_xor((int)u1[i], st);
            unsigned w2 = (unsigned)__shfl_xor((int)u2[i], st);
            unsigned a = umin_(u1[i], w1), b = umax_(u1[i], w1);
            u1[i] = a;
            u2[i] = umin_(umin_(u2[i], w2), b);
        }
    }
    if (L == 0) {
        const size_t gbase = (size_t)(blockIdx.y * 2 + chalf) * N_ROWS;
#pragma unroll
        for (int mt = 0; mt < 4; ++mt)
#pragma unroll
            for (int reg = 0; reg < 4; ++reg) {
                const int row = row0 + whalf * 64 + mt * 16 + quad * 4 + reg;
                top2_out[gbase + row] = make_uint2(u1[mt * 4 + reg], u2[mt * 4 + reg]);
            }
    }

    // ---- flush block-local colmin to private slice (plain stores) ----
    __syncthreads();   // drains vmcnt (incl. dead wrap stages) + lgkm
    unsigned* cp = colmin_part + (size_t)blockIdx.x * KCODES + code0;
    cp[t]       = colmin_l[t];
    cp[t + 256] = colmin_l[t + 256];
}

// ---- refine + gather + MSE, fused. grid = N_ROWS/4, 1 wave per row. ----
// R17: lane-parallel candidate selection (u64 key = score32|id32, same
// (v,id) lexicographic order). Fast path: (min1,min2) butterfly. Slow
// path: 8x extract-min recovers the identical top-8 set, then fp64
// re-score. R21: per-lane p[k]=cc2-2dd partials -> 9-value fp64 reduce.
__global__ __launch_bounds__(256) void vq_refine_kernel(
        const float* __restrict__ x, const float* __restrict__ cb,
        const uint2* __restrict__ top2, unsigned* __restrict__ active,
        float* __restrict__ out, double* __restrict__ accum) {
    __shared__ double wsum[4];
    const int wave = threadIdx.x >> 6, lane = threadIdx.x & 63;
    const int row  = blockIdx.x * 4 + wave;

    // lane-owned candidate -> packed u64 (quantized-score | id)
    const int g = (lane >> 1) & 15;
    uint2 e = top2[(size_t)g * N_ROWS + row];
    unsigned key = (lane & 1) ? e.y : e.x;
    unsigned idc = (unsigned)((g >> 1) * KC) + (key & 0x1FFu);
    unsigned long long pk =
        ((unsigned long long)(key & 0xFFFFFE00u) << 32) | idc;
    if (lane >= 32) pk = ~0ull;

    // butterfly (min1, min2) across 64 lanes -- wave-uniform result
    unsigned long long m1 = pk, m2 = ~0ull;
#pragma unroll
    for (int o = 1; o < 64; o <<= 1) {
        unsigned long long w1 = (unsigned long long)__shfl_xor((long long)m1, o);
        unsigned long long w2 = (unsigned long long)__shfl_xor((long long)m2, o);
        unsigned long long lo = umin64_(m1, w1), hi = umax64_(m1, w1);
        m1 = lo;
        m2 = umin64_(umin64_(m2, w2), hi);
    }
    const float v0 = fkey_inv((unsigned)(m1 >> 32));
    const float v1 = fkey_inv((unsigned)(m2 >> 32));

    float4 xv = ((const float4*)(x + (size_t)row * DIM))[lane];
    int tok;
    if (v1 > v0 + 1.0e-2f) {
        tok = (int)(unsigned)(m1 & 0xFFFFFFFFu);
    } else {
        // recover top-8 ids (ascending (v,id) order) by repeated extract-min
        int id8[8];
        unsigned long long cur = pk;
#pragma unroll
        for (int k = 0; k < 8; ++k) {
            unsigned long long m = cur;
#pragma unroll
            for (int o = 1; o < 64; o <<= 1)
                m = umin64_(m, (unsigned long long)__shfl_xor((long long)m, o));
            id8[k] = (int)(unsigned)(m & 0xFFFFFFFFu);
            if (cur == m) cur = ~0ull;   // owning lane removes it
        }

        double xs64 = (double)xv.x * xv.x + (double)xv.y * xv.y
                    + (double)xv.z * xv.z + (double)xv.w * xv.w;
        double p[8];
#pragma unroll
        for (int k = 0; k < 8; ++k) {
            float4 c4 = ((const float4*)(cb + (size_t)id8[k] * DIM))[lane];
            double dd  = (double)xv.x * c4.x + (double)xv.y * c4.y
                       + (double)xv.z * c4.z + (double)xv.w * c4.w;
            double cc2 = (double)c4.x * c4.x + (double)c4.y * c4.y
                       + (double)c4.z * c4.z + (double)c4.w * c4.w;
            p[k] = cc2 - 2.0 * dd;       // per-lane partial of cc2 - 2 x.c
        }
#pragma unroll
        for (int o = 32; o; o >>= 1) {
            xs64 += __shfl_down(xs64, o);
#pragma unroll
            for (int k = 0; k < 8; ++k)
                p[k] += __shfl_down(p[k], o);
        }
        if (lane == 0) {
            double D[8], Dmin = 1e300;
#pragma unroll
            for (int k = 0; k < 8; ++k) {
                D[k] = xs64 + p[k];
                Dmin = fmin(Dmin, D[k]);
            }
            int e2; frexp(Dmin, &e2);
            double U   = ldexp(1.0, e2 - 1 - 23);     // ulp_fp32(Dmin)
            double thr = Dmin + 0.75 * U;
            tok = 0x7FFFFFFF;
#pragma unroll
            for (int k = 0; k < 8; ++k)
                if (D[k] <= thr && id8[k] < tok) tok = id8[k];
        }
        tok = __shfl(tok, 0);
    }

    if (lane == 0) active[tok] = 1u;
    float4 sel = ((const float4*)(cb + (size_t)tok * DIM))[lane];
    ((float4*)out)[(size_t)row * 64 + lane] = sel;
    float dx = sel.x - xv.x, dy = sel.y - xv.y, dz = sel.z - xv.z, dw = sel.w - xv.w;
    float s = dx * dx + dy * dy + dz * dz + dw * dw;
    for (int o = 32; o; o >>= 1) s += __shfl_down(s, o);
    if (lane == 0) wsum[wave] = (double)s;
    __syncthreads();
    if (threadIdx.x == 0) atomicAdd(accum, wsum[0] + wsum[1] + wsum[2] + wsum[3]);
}

// ---- final: 128-way colmin reduction + entropy + loss. grid = 16 blocks.
// Each block reduces 256 codes over the 128 row-block partials, adds its
// inactive-code entropy partial; the 16th finisher computes the loss.
__global__ __launch_bounds__(256) void vq_final_kernel(
        const unsigned* __restrict__ colmin_part, const unsigned* __restrict__ active,
        double* __restrict__ accum, unsigned* __restrict__ counter,
        float* __restrict__ out) {
    __shared__ double red[256];
    const int t = threadIdx.x;
    const int c = blockIdx.x * 256 + t;
    unsigned m = 0xFFFFFFFFu;
#pragma unroll 8
    for (int rb = 0; rb < NRB; ++rb)
        m = umin_(m, colmin_part[(size_t)rb * KCODES + c]);
    red[t] = (active[c] == 0u) ? (double)fkey_inv(m) : 0.0;
    __syncthreads();
    for (int o = 128; o; o >>= 1) {
        if (t < o) red[t] += red[t + o];
        __syncthreads();
    }
    if (t == 0) {
        atomicAdd(&accum[1], red[0]);
        __threadfence();
        unsigned old = atomicAdd(counter, 1u);
        if (old == 15u) {
            __threadfence();
            double ent = atomicAdd(&accum[1], 0.0);   // atomic read
            double loss = 1.25 * (accum[0] / (double)((size_t)N_ROWS * DIM))
                        + 0.02 * (ent / (double)KCODES);
            out[(size_t)N_ROWS * DIM] = (float)loss;
        }
    }
}

extern "C" void kernel_launch(void* const* d_in, const int* in_sizes, int n_in,
                              void* d_out, int out_size, void* d_ws, size_t ws_size,
                              hipStream_t stream) {
    const float* x  = (const float*)d_in[0];   // [16384, 256]
    const float* cb = (const float*)d_in[1];   // [4096, 256]
    float* out = (float*)d_out;                // [16384*256] ++ [1] loss

    char* ws = (char*)d_ws;
    float*    xsq     = (float*)(ws + 0);                      // 64 KB
    float*    csq     = (float*)(ws + 65536);                  // 16 KB
    unsigned* active  = (unsigned*)(ws + 81920);               // 16 KB
    double*   accum   = (double*)(ws + 98304);                 // 256 B (mse, entropy)
    unsigned* counter = (unsigned*)(ws + 98560);               // 64 B
    uint2*    top2    = (uint2*)(ws + 131072);                 // 2 MB (16 granules)
    unsigned* cpart   = (unsigned*)(ws + 2228224);             // 2 MB (128 x 4096)
    unsigned short* xh_g = (unsigned short*)(ws + 4325376);    // 8 MB
    unsigned short* ch_g = (unsigned short*)(ws + 12713984);   // 2 MB (~14.2 MB)

    vq_prep_kernel<<<((N_ROWS + KCODES) * DIM) / 1024, 256, 0, stream>>>(
        x, cb, xh_g, ch_g, xsq, csq, active, accum, counter);
    vq_gemm_kernel<<<dim3(NRB, NCHUNK), 256, 0, stream>>>(
        xh_g, ch_g, xsq, csq, cpart, top2);
    vq_refine_kernel<<<N_ROWS / 4, 256, 0, stream>>>(
        x, cb, top2, active, out, accum);
    vq_final_kernel<<<KCODES / 256, 256, 0, stream>>>(
        cpart, active, accum, counter, out);
}